// Round 4
// baseline (362.080 us; speedup 1.0000x reference)
//
#include <hip/hip_runtime.h>
#include <math.h>

// DoG seasonal: out[b,l,c] = (k1*x)(l) - (k2*x)(l), depthwise over c, reflect pad.
// k1: sigma=4.2 (35 taps) exact. k2: sigma=96 (769 taps) via Gaussian pyramid:
//   G96 = G12 * G95.25 ; stage A: d[j] = (G12*x)(16j) (97 taps, decimate by 16)
//   stage B: e = gb * d on coarse grid (49 taps)
//   stage C (narrow): exact 35-tap conv + linear interp of e + subtract.
// Round-2 lesson: narrow MUST use gather form (static acc indexing) - scatter
//   form went to scratch (VGPR=44, 790us).
// Round-3 lesson: narrow is latency-bound at 4 waves/SIMD (VGPR~110), not
//   request-bound (16-out and 32-out both ~106us). This round: 8 outputs/thread,
//   ~58 VGPR, launch_bounds(256,7) -> 7-8 waves/SIMD.

#define Bdim 32
#define Ldim 4096
#define Cdim 321

#define R1 17
#define K1n 35
#define R2 384
#define K2n 769

#define GA_R 48
#define GA_N 97          // sigma_a = 12
#define GB_R 24
#define GB_N 49          // sigma_b = sqrt(96^2-12^2)/16 on coarse grid

#define NG 257           // e grid: j = 0..256 at l = 16j
#define NJD 305          // d grid: jj = -24..280 stored at jj+24
#define NGRP_A 20        // stage A: groups of 16 d-points
#define NSEG8 512        // narrow: segments of 8 outputs
#define NTJ 33           // stage B: groups of 8 outputs

// workspace float offsets
#define GA_OFF 0
#define GB_OFF 128
#define W1_OFF 192
#define K2_OFF 256       // 769 linear taps (naive fallback)
#define K2P_OFF 1088     // 784 polyphase-padded taps (middle fallback)
#define E2_OFF 4096      // middle-path e grid
#define D_OFF 4096       // pyramid d grid
#define E_OFF (D_OFF + Bdim*NJD*Cdim)            // 4096 + 3,132,960
#define WS_TOT (E_OFF + Bdim*NG*Cdim)            // + 2,639,904 floats

__device__ __forceinline__ int mirror_idx(int a) {
    a = a < 0 ? -a : a;
    a = a > (Ldim - 1) ? 2 * (Ldim - 1) - a : a;
    return a;
}

__device__ __forceinline__ int xcd_swizzle(int bid, int nwg) {
    // bijective XCD-chunk remap (m204): consecutive logical ids land on one XCD
    int q = nwg >> 3, r = nwg & 7;
    int xcd = bid & 7, i = bid >> 3;
    int base = (xcd < r) ? xcd * (q + 1) : r * (q + 1) + (xcd - r) * q;
    return base + i;
}

__device__ __forceinline__ float block_sum_1024(float v, float* partial) {
#pragma unroll
    for (int off = 32; off >= 1; off >>= 1) v += __shfl_down(v, off, 64);
    __syncthreads();                 // protect partial[] from previous use
    if ((threadIdx.x & 63) == 0) partial[threadIdx.x >> 6] = v;
    __syncthreads();
    float s = partial[0];
#pragma unroll
    for (int i = 1; i < 16; ++i) s += partial[i];
    return s;
}

__global__ void init_weights_kernel(float* __restrict__ w) {
    __shared__ float partial[16];
    const int tid = threadIdx.x;  // 1024 threads

    // ga: sigma 12, radius 48
    {
        float v = 0.f;
        if (tid < GA_N) { float t = (float)(tid - GA_R) * (1.0f / 12.0f); v = expf(-0.5f * t * t); }
        float s = block_sum_1024(v, partial);
        if (tid < GA_N) w[GA_OFF + tid] = v / s;
    }
    // gb: sigma sqrt(96^2-12^2)/16, radius 24
    {
        const float sb = sqrtf(96.f * 96.f - 12.f * 12.f) * (1.0f / 16.0f);
        float v = 0.f;
        if (tid < GB_N) { float t = (float)(tid - GB_R) / sb; v = expf(-0.5f * t * t); }
        float s = block_sum_1024(v, partial);
        if (tid < GB_N) w[GB_OFF + tid] = v / s;
    }
    // w1: sigma 4.2, radius 17
    {
        float v = 0.f;
        if (tid < K1n) { float t = (float)(tid - R1) * (1.0f / 4.2f); v = expf(-0.5f * t * t); }
        float s = block_sum_1024(v, partial);
        if (tid < K1n) w[W1_OFF + tid] = v / s;
    }
    // k2: sigma 96, radius 384 (fallback paths)
    {
        float v = 0.f;
        if (tid < K2n) { float t = (float)(tid - R2) * (1.0f / 96.0f); v = expf(-0.5f * t * t); }
        float s = block_sum_1024(v, partial);
        if (tid < K2n) w[K2_OFF + tid] = v / s;
        if (tid < 784) w[K2P_OFF + tid] = (tid < K2n) ? v / s : 0.f;
    }
}

// ---- Stage A: d[b, jj+24, c] = sum_t ga[t] * x~[16*jj - 48 + t], jj in [-24,280]
// polyphase over p = t mod 16; 16 d-points per thread, streaming row window.
__global__ __launch_bounds__(256) void decimA_kernel(
        const float* __restrict__ x, const float* __restrict__ ga,
        float* __restrict__ d) {
    __shared__ float gs[GA_N];
    if (threadIdx.x < GA_N) gs[threadIdx.x] = ga[threadIdx.x];
    __syncthreads();

    const int lb = xcd_swizzle(blockIdx.x, gridDim.x);
    const int lin = lb * 256 + threadIdx.x;
    const int c = lin % Cdim;
    const int rest = lin / Cdim;
    const int g = rest % NGRP_A;
    const int b = rest / NGRP_A;
    if (b >= Bdim) return;

    const int jj0 = -24 + 16 * g;
    const float* xb = x + b * (Ldim * Cdim) + c;

    float acc[16];
#pragma unroll
    for (int ii = 0; ii < 16; ++ii) acc[ii] = 0.f;

    const bool interior = (jj0 >= 3) && (jj0 <= 237);

#pragma unroll 1
    for (int p = 0; p < 16; ++p) {
        float row[22];
        if (interior) {
            const float* xp = xb + (16 * (jj0 - 3) + p) * Cdim;
#pragma unroll
            for (int i = 0; i < 22; ++i) row[i] = xp[i * (16 * Cdim)];
        } else {
#pragma unroll
            for (int i = 0; i < 22; ++i)
                row[i] = xb[mirror_idx(16 * (jj0 - 3 + i) + p) * Cdim];
        }
#pragma unroll
        for (int q = 0; q < 6; ++q) {
            const float wq = gs[16 * q + p];
#pragma unroll
            for (int ii = 0; ii < 16; ++ii)
                acc[ii] = fmaf(wq, row[ii + q], acc[ii]);
        }
        if (p == 0) {  // tap t=96 exists only for phase 0
            const float w6 = gs[96];
#pragma unroll
            for (int ii = 0; ii < 16; ++ii)
                acc[ii] = fmaf(w6, row[ii + 6], acc[ii]);
        }
    }

    const int j0d = jj0 + 24;   // 0..304, multiple of 16
    float* db = d + (b * NJD + j0d) * Cdim + c;
#pragma unroll
    for (int ii = 0; ii < 16; ++ii)
        if (j0d + ii < NJD) db[ii * Cdim] = acc[ii];
}

// ---- Stage B: e[b, j, c] = sum_s gb[s] * d[b, j+s, c], j in [0,256]
// gather form: row window in registers, static acc indexing.
__global__ __launch_bounds__(256) void coarseB_kernel(
        const float* __restrict__ d, const float* __restrict__ gb,
        float* __restrict__ e) {
    __shared__ float gbs[GB_N];
    if (threadIdx.x < GB_N) gbs[threadIdx.x] = gb[threadIdx.x];
    __syncthreads();

    const int lin = blockIdx.x * 256 + threadIdx.x;
    const int c = lin % Cdim;
    const int rest = lin / Cdim;
    const int tj = rest % NTJ;
    const int b = rest / NTJ;
    if (b >= Bdim) return;

    const int j0 = tj * 8;
    const float* db = d + b * (NJD * Cdim) + c;

    float row[56];
#pragma unroll
    for (int r = 0; r < 56; ++r) {
        int idx = j0 + r;
        idx = idx > (NJD - 1) ? (NJD - 1) : idx;   // clamp for the tail group
        row[r] = db[idx * Cdim];
    }

    float acc[8];
#pragma unroll
    for (int jj = 0; jj < 8; ++jj) acc[jj] = 0.f;
#pragma unroll
    for (int s = 0; s < GB_N; ++s) {
        const float wv = gbs[s];
#pragma unroll
        for (int jj = 0; jj < 8; ++jj)
            acc[jj] = fmaf(wv, row[s + jj], acc[jj]);
    }

    float* eb = e + (b * NG + j0) * Cdim + c;
#pragma unroll
    for (int jj = 0; jj < 8; ++jj)
        if (j0 + jj < NG) eb[jj * Cdim] = acc[jj];
}

// ---- Stage C: narrow conv (exact) + linear interp of e + subtract.
// 8 outputs/thread, GATHER form, ~58 VGPR target -> 7-8 waves/SIMD.
__global__ __launch_bounds__(256, 7) void narrow_kernel(
        const float* __restrict__ x, const float* __restrict__ w1,
        const float* __restrict__ e, float* __restrict__ out) {
    __shared__ float ws[K1n];
    if (threadIdx.x < K1n) ws[threadIdx.x] = w1[threadIdx.x];
    __syncthreads();

    const int lb = xcd_swizzle(blockIdx.x, gridDim.x);
    const int lin = lb * 256 + threadIdx.x;
    const int c = lin % Cdim;
    const int rest = lin / Cdim;
    const int seg = rest % NSEG8;       // 512 segments of 8 outputs
    const int b = rest / NSEG8;
    if (b >= Bdim) return;

    const int l0 = seg * 8;
    const float* xb = x + b * (Ldim * Cdim) + c;

    // row window: 42 rows covering taps for 8 outputs
    float row[42];
    if (seg >= 3 && seg <= 508) {
        const float* xp = xb + (l0 - R1) * Cdim;
#pragma unroll
        for (int i = 0; i < 42; ++i) row[i] = xp[i * Cdim];
    } else {
#pragma unroll
        for (int i = 0; i < 42; ++i)
            row[i] = xb[mirror_idx(l0 - R1 + i) * Cdim];
    }

    float acc[8];
#pragma unroll
    for (int m = 0; m < 8; ++m) acc[m] = 0.f;
#pragma unroll
    for (int t = 0; t < K1n; ++t) {
        const float wt = ws[t];   // LDS broadcast (wave-uniform)
#pragma unroll
        for (int m = 0; m < 8; ++m)
            acc[m] = fmaf(wt, row[t + m], acc[m]);
    }

    // e interp: outputs l0..l0+7 lie within [16j, 16(j+1)), j = l0>>4
    const int j = l0 >> 4;
    const float* eb = e + (b * NG + j) * Cdim + c;
    const float z0 = eb[0];
    const float z1 = eb[Cdim];
    const float dz = (z1 - z0) * (1.0f / 16.0f);
    const float f0 = (float)(l0 & 15);

    float* ob = out + (b * Ldim + l0) * Cdim + c;
#pragma unroll
    for (int m = 0; m < 8; ++m)
        ob[m * Cdim] = acc[m] - fmaf(dz, f0 + (float)m, z0);
}

// ---- Middle fallback: direct 769-tap wide conv on the stride-16 grid (round-1)
#define JPT 16
#define NJG 17
__global__ __launch_bounds__(256, 2) void wide_mid_kernel(
        const float* __restrict__ x, const float* __restrict__ w2p,
        float* __restrict__ z) {
    __shared__ float w2s[784];
    for (int i = threadIdx.x; i < 784; i += 256) w2s[i] = w2p[i];
    __syncthreads();

    const int gid = blockIdx.x * 256 + threadIdx.x;
    const int c = gid % Cdim;
    const int rest = gid / Cdim;
    const int jg = rest % NJG;
    const int b = rest / NJG;
    if (b >= Bdim) return;

    const int j0 = jg * JPT;
    const float* xb = x + b * (Ldim * Cdim) + c;

    float acc[JPT];
#pragma unroll
    for (int jj = 0; jj < JPT; ++jj) acc[jj] = 0.f;

    const bool interior = (j0 >= 24) && (16 * (j0 + 39) + 15 <= Ldim - 1);

#pragma unroll 1
    for (int p = 0; p < 16; ++p) {
        float row[64];
        if (interior) {
            const float* xp = xb + (16 * (j0 - 24) + p) * Cdim;
#pragma unroll
            for (int i = 0; i < 64; ++i) row[i] = xp[i * (16 * Cdim)];
        } else {
#pragma unroll
            for (int i = 0; i < 64; ++i)
                row[i] = xb[mirror_idx(16 * (j0 - 24 + i) + p) * Cdim];
        }
#pragma unroll
        for (int q = 0; q < 49; ++q) {
            const float wq = w2s[q * 16 + p];
#pragma unroll
            for (int jj = 0; jj < JPT; ++jj)
                acc[jj] = fmaf(wq, row[q + jj], acc[jj]);
        }
    }

    float* zb = z + (b * NG + j0) * Cdim + c;
#pragma unroll
    for (int jj = 0; jj < JPT; ++jj)
        if (j0 + jj < NG) zb[jj * Cdim] = acc[jj];
}

// ---- Last-resort fallback: fully direct
__global__ __launch_bounds__(256) void naive_kernel(
        const float* __restrict__ x, const float* __restrict__ w,
        float* __restrict__ out) {
    const int gid = blockIdx.x * 256 + threadIdx.x;
    if (gid >= Bdim * Ldim * Cdim) return;
    const int c = gid % Cdim;
    const int rest = gid / Cdim;
    const int l = rest % Ldim;
    const int b = rest / Ldim;
    const float* xb = x + b * (Ldim * Cdim) + c;
    float a2 = 0.f, a1 = 0.f;
    for (int t = 0; t < K2n; ++t)
        a2 = fmaf(w[K2_OFF + t], xb[mirror_idx(l + t - R2) * Cdim], a2);
#pragma unroll
    for (int t = 0; t < K1n; ++t)
        a1 = fmaf(w[W1_OFF + t], xb[mirror_idx(l + t - R1) * Cdim], a1);
    out[gid] = a1 - a2;
}

extern "C" void kernel_launch(void* const* d_in, const int* in_sizes, int n_in,
                              void* d_out, int out_size, void* d_ws, size_t ws_size,
                              hipStream_t stream) {
    (void)in_sizes; (void)n_in; (void)out_size;
    const float* x = (const float*)d_in[0];
    float* out = (float*)d_out;
    float* w = (float*)d_ws;

    hipLaunchKernelGGL(init_weights_kernel, dim3(1), dim3(1024), 0, stream, w);

    const size_t need_pyr = (size_t)WS_TOT * sizeof(float);
    const size_t need_mid = (size_t)(E2_OFF + Bdim * NG * Cdim) * sizeof(float);

    const int nar_total = Bdim * NSEG8 * Cdim;         // 5,259,264
    const dim3 nar_grid((nar_total + 255) / 256);      // 20544 blocks

    if (ws_size >= need_pyr) {
        const int a_total = Bdim * NGRP_A * Cdim;      // 205,440
        hipLaunchKernelGGL(decimA_kernel, dim3((a_total + 255) / 256), dim3(256),
                           0, stream, x, w + GA_OFF, w + D_OFF);
        const int b_total = Bdim * NTJ * Cdim;         // 338,976
        hipLaunchKernelGGL(coarseB_kernel, dim3((b_total + 255) / 256), dim3(256),
                           0, stream, w + D_OFF, w + GB_OFF, w + E_OFF);
        hipLaunchKernelGGL(narrow_kernel, nar_grid, dim3(256),
                           0, stream, x, w + W1_OFF, w + E_OFF, out);
    } else if (ws_size >= need_mid) {
        const int wide_total = Bdim * NJG * Cdim;      // 174,624
        hipLaunchKernelGGL(wide_mid_kernel, dim3((wide_total + 255) / 256), dim3(256),
                           0, stream, x, w + K2P_OFF, w + E2_OFF);
        hipLaunchKernelGGL(narrow_kernel, nar_grid, dim3(256),
                           0, stream, x, w + W1_OFF, w + E2_OFF, out);
    } else {
        const int total = Bdim * Ldim * Cdim;
        hipLaunchKernelGGL(naive_kernel, dim3((total + 255) / 256), dim3(256),
                           0, stream, x, w, out);
    }
}

// Round 5
// 170.643 us; speedup vs baseline: 2.1219x; 2.1219x over previous
//
#include <hip/hip_runtime.h>
#include <math.h>

// DoG seasonal: out[b,l,c] = (k1*x)(l) - (k2*x)(l), depthwise over c, reflect pad.
// k1: sigma=4.2 (35 taps) exact. k2: sigma=96 (769 taps) via Gaussian pyramid:
//   G96 = G12 * G95.25 ; stage A: d[j] = (G12*x)(16j) (97 taps, decimate by 16)
//   stage B: e = gb * d on coarse grid (49 taps)
//   stage C (narrow): exact 35-tap conv + linear interp of e + subtract.
// Round-2 lesson: narrow MUST be gather-form (static indexing) - scatter spilled.
// Round-4 lesson: never cap VGPR below the register-array footprint
//   (launch_bounds(256,7) + row[42] -> spill -> 300us).
// Round-5: narrow is HBM-bytes bound (~2x read amplification in register form;
//   insensitive to occupancy r1/r3). LDS-tiled: 64l x 64c tile, 98-row stage,
//   amplification 1.53x, halo reuse via L2 + XCD swizzle.

#define Bdim 32
#define Ldim 4096
#define Cdim 321

#define R1 17
#define K1n 35
#define R2 384
#define K2n 769

#define GA_R 48
#define GA_N 97          // sigma_a = 12
#define GB_R 24
#define GB_N 49          // sigma_b = sqrt(96^2-12^2)/16 on coarse grid

#define NG 257           // e grid: j = 0..256 at l = 16j
#define NJD 305          // d grid: jj = -24..280 stored at jj+24
#define NGRP_A 20        // stage A: groups of 16 d-points
#define NTJ 33           // stage B: groups of 8 outputs

// narrow LDS tiling
#define TL 64            // outputs per tile along l
#define TROWS 98         // TL + 2*R1
#define NLT 64           // Ldim/TL
#define NCT 6            // c tiles: c0 = 0,64,128,192,256,257(overlap)
#define NSEG 128         // reg-form fallback: segments of 32 outputs

// workspace float offsets
#define GA_OFF 0
#define GB_OFF 128
#define W1_OFF 192
#define K2_OFF 256       // 769 linear taps (naive fallback)
#define K2P_OFF 1088     // 784 polyphase-padded taps (middle fallback)
#define E2_OFF 4096      // middle-path e grid
#define D_OFF 4096       // pyramid d grid
#define E_OFF (D_OFF + Bdim*NJD*Cdim)            // 4096 + 3,132,960
#define WS_TOT (E_OFF + Bdim*NG*Cdim)            // + 2,639,904 floats

__device__ __forceinline__ int mirror_idx(int a) {
    a = a < 0 ? -a : a;
    a = a > (Ldim - 1) ? 2 * (Ldim - 1) - a : a;
    return a;
}

__device__ __forceinline__ int xcd_swizzle(int bid, int nwg) {
    // bijective XCD-chunk remap (m204)
    int q = nwg >> 3, r = nwg & 7;
    int xcd = bid & 7, i = bid >> 3;
    int base = (xcd < r) ? xcd * (q + 1) : r * (q + 1) + (xcd - r) * q;
    return base + i;
}

__device__ __forceinline__ float block_sum_1024(float v, float* partial) {
#pragma unroll
    for (int off = 32; off >= 1; off >>= 1) v += __shfl_down(v, off, 64);
    __syncthreads();
    if ((threadIdx.x & 63) == 0) partial[threadIdx.x >> 6] = v;
    __syncthreads();
    float s = partial[0];
#pragma unroll
    for (int i = 1; i < 16; ++i) s += partial[i];
    return s;
}

__global__ void init_weights_kernel(float* __restrict__ w) {
    __shared__ float partial[16];
    const int tid = threadIdx.x;  // 1024 threads

    {   // ga: sigma 12, radius 48
        float v = 0.f;
        if (tid < GA_N) { float t = (float)(tid - GA_R) * (1.0f / 12.0f); v = expf(-0.5f * t * t); }
        float s = block_sum_1024(v, partial);
        if (tid < GA_N) w[GA_OFF + tid] = v / s;
    }
    {   // gb
        const float sb = sqrtf(96.f * 96.f - 12.f * 12.f) * (1.0f / 16.0f);
        float v = 0.f;
        if (tid < GB_N) { float t = (float)(tid - GB_R) / sb; v = expf(-0.5f * t * t); }
        float s = block_sum_1024(v, partial);
        if (tid < GB_N) w[GB_OFF + tid] = v / s;
    }
    {   // w1: sigma 4.2
        float v = 0.f;
        if (tid < K1n) { float t = (float)(tid - R1) * (1.0f / 4.2f); v = expf(-0.5f * t * t); }
        float s = block_sum_1024(v, partial);
        if (tid < K1n) w[W1_OFF + tid] = v / s;
    }
    {   // k2: sigma 96 (fallbacks)
        float v = 0.f;
        if (tid < K2n) { float t = (float)(tid - R2) * (1.0f / 96.0f); v = expf(-0.5f * t * t); }
        float s = block_sum_1024(v, partial);
        if (tid < K2n) w[K2_OFF + tid] = v / s;
        if (tid < 784) w[K2P_OFF + tid] = (tid < K2n) ? v / s : 0.f;
    }
}

// ---- Stage A: d[b, jj+24, c], polyphase decimate-by-16 with G12 (97 taps)
__global__ __launch_bounds__(256) void decimA_kernel(
        const float* __restrict__ x, const float* __restrict__ ga,
        float* __restrict__ d) {
    __shared__ float gs[GA_N];
    if (threadIdx.x < GA_N) gs[threadIdx.x] = ga[threadIdx.x];
    __syncthreads();

    const int lb = xcd_swizzle(blockIdx.x, gridDim.x);
    const int lin = lb * 256 + threadIdx.x;
    const int c = lin % Cdim;
    const int rest = lin / Cdim;
    const int g = rest % NGRP_A;
    const int b = rest / NGRP_A;
    if (b >= Bdim) return;

    const int jj0 = -24 + 16 * g;
    const float* xb = x + b * (Ldim * Cdim) + c;

    float acc[16];
#pragma unroll
    for (int ii = 0; ii < 16; ++ii) acc[ii] = 0.f;

    const bool interior = (jj0 >= 3) && (jj0 <= 237);

#pragma unroll 1
    for (int p = 0; p < 16; ++p) {
        float row[22];
        if (interior) {
            const float* xp = xb + (16 * (jj0 - 3) + p) * Cdim;
#pragma unroll
            for (int i = 0; i < 22; ++i) row[i] = xp[i * (16 * Cdim)];
        } else {
#pragma unroll
            for (int i = 0; i < 22; ++i)
                row[i] = xb[mirror_idx(16 * (jj0 - 3 + i) + p) * Cdim];
        }
#pragma unroll
        for (int q = 0; q < 6; ++q) {
            const float wq = gs[16 * q + p];
#pragma unroll
            for (int ii = 0; ii < 16; ++ii)
                acc[ii] = fmaf(wq, row[ii + q], acc[ii]);
        }
        if (p == 0) {
            const float w6 = gs[96];
#pragma unroll
            for (int ii = 0; ii < 16; ++ii)
                acc[ii] = fmaf(w6, row[ii + 6], acc[ii]);
        }
    }

    const int j0d = jj0 + 24;
    float* db = d + (b * NJD + j0d) * Cdim + c;
#pragma unroll
    for (int ii = 0; ii < 16; ++ii)
        if (j0d + ii < NJD) db[ii * Cdim] = acc[ii];
}

// ---- Stage B: e = gb * d on coarse grid
__global__ __launch_bounds__(256) void coarseB_kernel(
        const float* __restrict__ d, const float* __restrict__ gb,
        float* __restrict__ e) {
    __shared__ float gbs[GB_N];
    if (threadIdx.x < GB_N) gbs[threadIdx.x] = gb[threadIdx.x];
    __syncthreads();

    const int lin = blockIdx.x * 256 + threadIdx.x;
    const int c = lin % Cdim;
    const int rest = lin / Cdim;
    const int tj = rest % NTJ;
    const int b = rest / NTJ;
    if (b >= Bdim) return;

    const int j0 = tj * 8;
    const float* db = d + b * (NJD * Cdim) + c;

    float row[56];
#pragma unroll
    for (int r = 0; r < 56; ++r) {
        int idx = j0 + r;
        idx = idx > (NJD - 1) ? (NJD - 1) : idx;
        row[r] = db[idx * Cdim];
    }

    float acc[8];
#pragma unroll
    for (int jj = 0; jj < 8; ++jj) acc[jj] = 0.f;
#pragma unroll
    for (int s = 0; s < GB_N; ++s) {
        const float wv = gbs[s];
#pragma unroll
        for (int jj = 0; jj < 8; ++jj)
            acc[jj] = fmaf(wv, row[s + jj], acc[jj]);
    }

    float* eb = e + (b * NG + j0) * Cdim + c;
#pragma unroll
    for (int jj = 0; jj < 8; ++jj)
        if (j0 + jj < NG) eb[jj * Cdim] = acc[jj];
}

// ---- Stage C: LDS-tiled narrow conv + interp + subtract.
// Block: 256 threads = 64l x 64c tile. Stage 98 rows x 64c into LDS (25 KB),
// each thread then gathers 50 values for its column into registers and
// computes 16 outputs. c-tile 5 overlaps tile 4 (idempotent writes) so no masks.
__global__ __launch_bounds__(256, 4) void narrow_lds_kernel(
        const float* __restrict__ x, const float* __restrict__ w1,
        const float* __restrict__ e, float* __restrict__ out) {
    __shared__ float ws[K1n];
    __shared__ float tile[TROWS * 64];
    if (threadIdx.x < K1n) ws[threadIdx.x] = w1[threadIdx.x];

    const int bid = xcd_swizzle(blockIdx.x, gridDim.x);
    // bid = (b*NCT + ct)*NLT + lt  (lt innermost: adjacent blocks share halos)
    const int lt = bid % NLT;
    const int rest = bid / NLT;
    const int ct = rest % NCT;
    const int b = rest / NCT;

    const int c = threadIdx.x & 63;
    const int wv = threadIdx.x >> 6;          // wave id 0..3
    const int c0 = (ct < 5) ? ct * 64 : Cdim - 64;   // 0,64,128,192,256,257
    const int l0 = lt * TL;
    const float* xb = x + b * (Ldim * Cdim);

    // ---- stage 98 rows, coalesced 256B per row per wave
    if (lt > 0 && lt < NLT - 1) {
        const float* xp = xb + (l0 - R1) * Cdim + c0 + c;
#pragma unroll
        for (int k = 0; k < 25; ++k) {
            const int r = wv + 4 * k;
            if (r < TROWS) tile[r * 64 + c] = xp[r * Cdim];
        }
    } else {
#pragma unroll
        for (int k = 0; k < 25; ++k) {
            const int r = wv + 4 * k;
            if (r < TROWS) tile[r * 64 + c] = xb[mirror_idx(l0 - R1 + r) * Cdim + c0 + c];
        }
    }
    __syncthreads();

    // ---- compute 16 outputs at l = l0 + wv*16 + m, column c0+c
    float row[50];
#pragma unroll
    for (int i = 0; i < 50; ++i) row[i] = tile[(wv * 16 + i) * 64 + c];

    float acc[16];
#pragma unroll
    for (int m = 0; m < 16; ++m) acc[m] = 0.f;
#pragma unroll
    for (int t = 0; t < K1n; ++t) {
        const float wt = ws[t];
#pragma unroll
        for (int m = 0; m < 16; ++m)
            acc[m] = fmaf(wt, row[t + m], acc[m]);
    }

    // ---- e interp: this thread's 16 l's span exactly one coarse interval
    const int j = (l0 >> 4) + wv;
    const float* eb = e + (b * NG + j) * Cdim + c0 + c;
    const float z0 = eb[0];
    const float z1 = eb[Cdim];
    const float dz = (z1 - z0) * (1.0f / 16.0f);

    float* ob = out + (b * Ldim + l0 + wv * 16) * Cdim + c0 + c;
#pragma unroll
    for (int m = 0; m < 16; ++m)
        ob[m * Cdim] = acc[m] - fmaf(dz, (float)m, z0);
}

// ---- reg-form narrow (middle-fallback path), proven round-3 structure
__global__ __launch_bounds__(256, 2) void narrow_reg_kernel(
        const float* __restrict__ x, const float* __restrict__ w1,
        const float* __restrict__ e, float* __restrict__ out) {
    __shared__ float ws[K1n];
    if (threadIdx.x < K1n) ws[threadIdx.x] = w1[threadIdx.x];
    __syncthreads();

    const int lb = xcd_swizzle(blockIdx.x, gridDim.x);
    const int lin = lb * 256 + threadIdx.x;
    const int c = lin % Cdim;
    const int rest = lin / Cdim;
    const int seg = rest % NSEG;
    const int b = rest / NSEG;
    if (b >= Bdim) return;

    const int l0 = seg * 32;
    const float* xb = x + b * (Ldim * Cdim) + c;

    const int j0 = seg * 2;
    const float* eb = e + (b * NG + j0) * Cdim + c;
    const float z0 = eb[0];
    const float z1 = eb[Cdim];
    const float z2 = eb[2 * Cdim];

    float row[66];
    if (seg >= 1 && seg <= 126) {
        const float* xp = xb + (l0 - R1) * Cdim;
#pragma unroll
        for (int i = 0; i < 66; ++i) row[i] = xp[i * Cdim];
    } else {
#pragma unroll
        for (int i = 0; i < 66; ++i)
            row[i] = xb[mirror_idx(l0 - R1 + i) * Cdim];
    }

    float acc[32];
#pragma unroll
    for (int m = 0; m < 32; ++m) acc[m] = 0.f;
#pragma unroll
    for (int t = 0; t < K1n; ++t) {
        const float wt = ws[t];
#pragma unroll
        for (int m = 0; m < 32; ++m)
            acc[m] = fmaf(wt, row[t + m], acc[m]);
    }

    const float d0 = (z1 - z0) * (1.0f / 16.0f);
    const float d1 = (z2 - z1) * (1.0f / 16.0f);
    float* ob = out + (b * Ldim + l0) * Cdim + c;
#pragma unroll
    for (int m = 0; m < 16; ++m)
        ob[m * Cdim] = acc[m] - fmaf(d0, (float)m, z0);
#pragma unroll
    for (int m = 16; m < 32; ++m)
        ob[m * Cdim] = acc[m] - fmaf(d1, (float)(m - 16), z1);
}

// ---- Middle fallback: direct 769-tap wide conv on the stride-16 grid
#define JPT 16
#define NJG 17
__global__ __launch_bounds__(256, 2) void wide_mid_kernel(
        const float* __restrict__ x, const float* __restrict__ w2p,
        float* __restrict__ z) {
    __shared__ float w2s[784];
    for (int i = threadIdx.x; i < 784; i += 256) w2s[i] = w2p[i];
    __syncthreads();

    const int gid = blockIdx.x * 256 + threadIdx.x;
    const int c = gid % Cdim;
    const int rest = gid / Cdim;
    const int jg = rest % NJG;
    const int b = rest / NJG;
    if (b >= Bdim) return;

    const int j0 = jg * JPT;
    const float* xb = x + b * (Ldim * Cdim) + c;

    float acc[JPT];
#pragma unroll
    for (int jj = 0; jj < JPT; ++jj) acc[jj] = 0.f;

    const bool interior = (j0 >= 24) && (16 * (j0 + 39) + 15 <= Ldim - 1);

#pragma unroll 1
    for (int p = 0; p < 16; ++p) {
        float row[64];
        if (interior) {
            const float* xp = xb + (16 * (j0 - 24) + p) * Cdim;
#pragma unroll
            for (int i = 0; i < 64; ++i) row[i] = xp[i * (16 * Cdim)];
        } else {
#pragma unroll
            for (int i = 0; i < 64; ++i)
                row[i] = xb[mirror_idx(16 * (j0 - 24 + i) + p) * Cdim];
        }
#pragma unroll
        for (int q = 0; q < 49; ++q) {
            const float wq = w2s[q * 16 + p];
#pragma unroll
            for (int jj = 0; jj < JPT; ++jj)
                acc[jj] = fmaf(wq, row[q + jj], acc[jj]);
        }
    }

    float* zb = z + (b * NG + j0) * Cdim + c;
#pragma unroll
    for (int jj = 0; jj < JPT; ++jj)
        if (j0 + jj < NG) zb[jj * Cdim] = acc[jj];
}

// ---- Last-resort fallback: fully direct
__global__ __launch_bounds__(256) void naive_kernel(
        const float* __restrict__ x, const float* __restrict__ w,
        float* __restrict__ out) {
    const int gid = blockIdx.x * 256 + threadIdx.x;
    if (gid >= Bdim * Ldim * Cdim) return;
    const int c = gid % Cdim;
    const int rest = gid / Cdim;
    const int l = rest % Ldim;
    const int b = rest / Ldim;
    const float* xb = x + b * (Ldim * Cdim) + c;
    float a2 = 0.f, a1 = 0.f;
    for (int t = 0; t < K2n; ++t)
        a2 = fmaf(w[K2_OFF + t], xb[mirror_idx(l + t - R2) * Cdim], a2);
#pragma unroll
    for (int t = 0; t < K1n; ++t)
        a1 = fmaf(w[W1_OFF + t], xb[mirror_idx(l + t - R1) * Cdim], a1);
    out[gid] = a1 - a2;
}

extern "C" void kernel_launch(void* const* d_in, const int* in_sizes, int n_in,
                              void* d_out, int out_size, void* d_ws, size_t ws_size,
                              hipStream_t stream) {
    (void)in_sizes; (void)n_in; (void)out_size;
    const float* x = (const float*)d_in[0];
    float* out = (float*)d_out;
    float* w = (float*)d_ws;

    hipLaunchKernelGGL(init_weights_kernel, dim3(1), dim3(1024), 0, stream, w);

    const size_t need_pyr = (size_t)WS_TOT * sizeof(float);
    const size_t need_mid = (size_t)(E2_OFF + Bdim * NG * Cdim) * sizeof(float);

    if (ws_size >= need_pyr) {
        const int a_total = Bdim * NGRP_A * Cdim;      // 205,440
        hipLaunchKernelGGL(decimA_kernel, dim3((a_total + 255) / 256), dim3(256),
                           0, stream, x, w + GA_OFF, w + D_OFF);
        const int b_total = Bdim * NTJ * Cdim;         // 338,976
        hipLaunchKernelGGL(coarseB_kernel, dim3((b_total + 255) / 256), dim3(256),
                           0, stream, w + D_OFF, w + GB_OFF, w + E_OFF);
        const int nblk = Bdim * NCT * NLT;             // 12,288 blocks
        hipLaunchKernelGGL(narrow_lds_kernel, dim3(nblk), dim3(256),
                           0, stream, x, w + W1_OFF, w + E_OFF, out);
    } else if (ws_size >= need_mid) {
        const int wide_total = Bdim * NJG * Cdim;
        hipLaunchKernelGGL(wide_mid_kernel, dim3((wide_total + 255) / 256), dim3(256),
                           0, stream, x, w + K2P_OFF, w + E2_OFF);
        const int nar_total = Bdim * NSEG * Cdim;
        hipLaunchKernelGGL(narrow_reg_kernel, dim3((nar_total + 255) / 256), dim3(256),
                           0, stream, x, w + W1_OFF, w + E2_OFF, out);
    } else {
        const int total = Bdim * Ldim * Cdim;
        hipLaunchKernelGGL(naive_kernel, dim3((total + 255) / 256), dim3(256),
                           0, stream, x, w, out);
    }
}

// Round 6
// 167.269 us; speedup vs baseline: 2.1647x; 1.0202x over previous
//
#include <hip/hip_runtime.h>
#include <math.h>

// DoG seasonal: out[b,l,c] = (k1*x)(l) - (k2*x)(l), depthwise over c, reflect pad.
// k1: sigma=4.2 (35 taps) exact. k2: sigma=96 (769 taps) via Gaussian pyramid:
//   G96 = G12 * G95.25 ; stage A: d[j] = (G12*x)(16j) (97 taps, decimate by 16)
//   stage B: e = gb * d on coarse grid (49 taps)
//   stage C (narrow): exact 35-tap conv + linear interp of e + subtract.
// Round-2: narrow MUST be gather-form (static indexing) - scatter spilled.
// Round-4: never cap VGPR below the register-array footprint (spill -> 300us).
// Round-5: narrow is VALU-issue bound (VALU 57%, BW 40%, FETCH only 104MB --
//   L3 absorbs re-reads). Round-6: pack 2 channels per thread ->
//   v_pk_fma_f32 (280 packed vs 560 scalar FMAs) + ds_read_b64.

#define Bdim 32
#define Ldim 4096
#define Cdim 321

#define R1 17
#define K1n 35
#define R2 384
#define K2n 769

#define GA_R 48
#define GA_N 97          // sigma_a = 12
#define GB_R 24
#define GB_N 49          // sigma_b = sqrt(96^2-12^2)/16 on coarse grid

#define NG 257           // e grid: j = 0..256 at l = 16j
#define NJD 305          // d grid: jj = -24..280 stored at jj+24
#define NGRP_A 20        // stage A: groups of 16 d-points
#define NTJ 33           // stage B: groups of 8 outputs

// narrow LDS tiling
#define TL 64            // outputs per tile along l
#define TROWS 98         // TL + 2*R1
#define NLT 64           // Ldim/TL
#define NCT 6            // c tiles: c0 = 0,64,128,192,256,257(overlap)
#define NSEG 128         // reg-form fallback: segments of 32 outputs

// workspace float offsets
#define GA_OFF 0
#define GB_OFF 128
#define W1_OFF 192
#define K2_OFF 256       // 769 linear taps (naive fallback)
#define K2P_OFF 1088     // 784 polyphase-padded taps (middle fallback)
#define E2_OFF 4096      // middle-path e grid
#define D_OFF 4096       // pyramid d grid
#define E_OFF (D_OFF + Bdim*NJD*Cdim)            // 4096 + 3,132,960
#define WS_TOT (E_OFF + Bdim*NG*Cdim)            // + 2,639,904 floats

typedef float f32x2 __attribute__((ext_vector_type(2)));

__device__ __forceinline__ int mirror_idx(int a) {
    a = a < 0 ? -a : a;
    a = a > (Ldim - 1) ? 2 * (Ldim - 1) - a : a;
    return a;
}

__device__ __forceinline__ int xcd_swizzle(int bid, int nwg) {
    // bijective XCD-chunk remap (m204)
    int q = nwg >> 3, r = nwg & 7;
    int xcd = bid & 7, i = bid >> 3;
    int base = (xcd < r) ? xcd * (q + 1) : r * (q + 1) + (xcd - r) * q;
    return base + i;
}

__device__ __forceinline__ float block_sum_1024(float v, float* partial) {
#pragma unroll
    for (int off = 32; off >= 1; off >>= 1) v += __shfl_down(v, off, 64);
    __syncthreads();
    if ((threadIdx.x & 63) == 0) partial[threadIdx.x >> 6] = v;
    __syncthreads();
    float s = partial[0];
#pragma unroll
    for (int i = 1; i < 16; ++i) s += partial[i];
    return s;
}

__global__ void init_weights_kernel(float* __restrict__ w) {
    __shared__ float partial[16];
    const int tid = threadIdx.x;  // 1024 threads

    {   // ga: sigma 12, radius 48
        float v = 0.f;
        if (tid < GA_N) { float t = (float)(tid - GA_R) * (1.0f / 12.0f); v = expf(-0.5f * t * t); }
        float s = block_sum_1024(v, partial);
        if (tid < GA_N) w[GA_OFF + tid] = v / s;
    }
    {   // gb
        const float sb = sqrtf(96.f * 96.f - 12.f * 12.f) * (1.0f / 16.0f);
        float v = 0.f;
        if (tid < GB_N) { float t = (float)(tid - GB_R) / sb; v = expf(-0.5f * t * t); }
        float s = block_sum_1024(v, partial);
        if (tid < GB_N) w[GB_OFF + tid] = v / s;
    }
    {   // w1: sigma 4.2
        float v = 0.f;
        if (tid < K1n) { float t = (float)(tid - R1) * (1.0f / 4.2f); v = expf(-0.5f * t * t); }
        float s = block_sum_1024(v, partial);
        if (tid < K1n) w[W1_OFF + tid] = v / s;
    }
    {   // k2: sigma 96 (fallbacks)
        float v = 0.f;
        if (tid < K2n) { float t = (float)(tid - R2) * (1.0f / 96.0f); v = expf(-0.5f * t * t); }
        float s = block_sum_1024(v, partial);
        if (tid < K2n) w[K2_OFF + tid] = v / s;
        if (tid < 784) w[K2P_OFF + tid] = (tid < K2n) ? v / s : 0.f;
    }
}

// ---- Stage A: d[b, jj+24, c], polyphase decimate-by-16 with G12 (97 taps)
__global__ __launch_bounds__(256) void decimA_kernel(
        const float* __restrict__ x, const float* __restrict__ ga,
        float* __restrict__ d) {
    __shared__ float gs[GA_N];
    if (threadIdx.x < GA_N) gs[threadIdx.x] = ga[threadIdx.x];
    __syncthreads();

    const int lb = xcd_swizzle(blockIdx.x, gridDim.x);
    const int lin = lb * 256 + threadIdx.x;
    const int c = lin % Cdim;
    const int rest = lin / Cdim;
    const int g = rest % NGRP_A;
    const int b = rest / NGRP_A;
    if (b >= Bdim) return;

    const int jj0 = -24 + 16 * g;
    const float* xb = x + b * (Ldim * Cdim) + c;

    float acc[16];
#pragma unroll
    for (int ii = 0; ii < 16; ++ii) acc[ii] = 0.f;

    const bool interior = (jj0 >= 3) && (jj0 <= 237);

#pragma unroll 1
    for (int p = 0; p < 16; ++p) {
        float row[22];
        if (interior) {
            const float* xp = xb + (16 * (jj0 - 3) + p) * Cdim;
#pragma unroll
            for (int i = 0; i < 22; ++i) row[i] = xp[i * (16 * Cdim)];
        } else {
#pragma unroll
            for (int i = 0; i < 22; ++i)
                row[i] = xb[mirror_idx(16 * (jj0 - 3 + i) + p) * Cdim];
        }
#pragma unroll
        for (int q = 0; q < 6; ++q) {
            const float wq = gs[16 * q + p];
#pragma unroll
            for (int ii = 0; ii < 16; ++ii)
                acc[ii] = fmaf(wq, row[ii + q], acc[ii]);
        }
        if (p == 0) {
            const float w6 = gs[96];
#pragma unroll
            for (int ii = 0; ii < 16; ++ii)
                acc[ii] = fmaf(w6, row[ii + 6], acc[ii]);
        }
    }

    const int j0d = jj0 + 24;
    float* db = d + (b * NJD + j0d) * Cdim + c;
#pragma unroll
    for (int ii = 0; ii < 16; ++ii)
        if (j0d + ii < NJD) db[ii * Cdim] = acc[ii];
}

// ---- Stage B: e = gb * d on coarse grid
__global__ __launch_bounds__(256) void coarseB_kernel(
        const float* __restrict__ d, const float* __restrict__ gb,
        float* __restrict__ e) {
    __shared__ float gbs[GB_N];
    if (threadIdx.x < GB_N) gbs[threadIdx.x] = gb[threadIdx.x];
    __syncthreads();

    const int lin = blockIdx.x * 256 + threadIdx.x;
    const int c = lin % Cdim;
    const int rest = lin / Cdim;
    const int tj = rest % NTJ;
    const int b = rest / NTJ;
    if (b >= Bdim) return;

    const int j0 = tj * 8;
    const float* db = d + b * (NJD * Cdim) + c;

    float row[56];
#pragma unroll
    for (int r = 0; r < 56; ++r) {
        int idx = j0 + r;
        idx = idx > (NJD - 1) ? (NJD - 1) : idx;
        row[r] = db[idx * Cdim];
    }

    float acc[8];
#pragma unroll
    for (int jj = 0; jj < 8; ++jj) acc[jj] = 0.f;
#pragma unroll
    for (int s = 0; s < GB_N; ++s) {
        const float wv = gbs[s];
#pragma unroll
        for (int jj = 0; jj < 8; ++jj)
            acc[jj] = fmaf(wv, row[s + jj], acc[jj]);
    }

    float* eb = e + (b * NG + j0) * Cdim + c;
#pragma unroll
    for (int jj = 0; jj < 8; ++jj)
        if (j0 + jj < NG) eb[jj * Cdim] = acc[jj];
}

// ---- Stage C: LDS-tiled narrow conv + interp + subtract, f32x2 packed.
// Block: 256 threads = 64l x 64c tile; LDS stage 98 rows x 64c (25.6 KB).
// Thread: channel-pair cp (2 adjacent c) x 8 l -> 42 ds_read_b64 window,
// 35 taps x 8 = 280 v_pk_fma_f32. Scalar stores (row base is 4-mod-8 for odd l).
__global__ __launch_bounds__(256, 3) void narrow_lds_kernel(
        const float* __restrict__ x, const float* __restrict__ w1,
        const float* __restrict__ e, float* __restrict__ out) {
    __shared__ float ws[K1n];
    __shared__ float tile[TROWS * 64];
    if (threadIdx.x < K1n) ws[threadIdx.x] = w1[threadIdx.x];

    const int bid = xcd_swizzle(blockIdx.x, gridDim.x);
    // bid = (b*NCT + ct)*NLT + lt  (lt innermost: adjacent blocks share halos)
    const int lt = bid % NLT;
    const int rest = bid / NLT;
    const int ct = rest % NCT;
    const int b = rest / NCT;

    const int c = threadIdx.x & 63;           // staging lane
    const int wv = threadIdx.x >> 6;          // wave id 0..3 (staging)
    const int c0 = (ct < 5) ? ct * 64 : Cdim - 64;   // 0,64,128,192,256,257
    const int l0 = lt * TL;
    const float* xb = x + b * (Ldim * Cdim);

    // ---- stage 98 rows, coalesced 256B per row per wave
    if (lt > 0 && lt < NLT - 1) {
        const float* xp = xb + (l0 - R1) * Cdim + c0 + c;
#pragma unroll
        for (int k = 0; k < 25; ++k) {
            const int r = wv + 4 * k;
            if (r < TROWS) tile[r * 64 + c] = xp[r * Cdim];
        }
    } else {
#pragma unroll
        for (int k = 0; k < 25; ++k) {
            const int r = wv + 4 * k;
            if (r < TROWS) tile[r * 64 + c] = xb[mirror_idx(l0 - R1 + r) * Cdim + c0 + c];
        }
    }
    __syncthreads();

    // ---- compute: thread = channel pair cp, l-group g (8 l's)
    const int cp = threadIdx.x & 31;          // columns c0+2cp, c0+2cp+1
    const int g = threadIdx.x >> 5;           // 0..7, l = l0 + g*8 + m
    const int lg = g * 8;

    f32x2 r2[42];
#pragma unroll
    for (int i = 0; i < 42; ++i)
        r2[i] = *reinterpret_cast<const f32x2*>(&tile[(lg + i) * 64 + 2 * cp]);

    f32x2 acc[8];
#pragma unroll
    for (int m = 0; m < 8; ++m) acc[m] = (f32x2)(0.f);
#pragma unroll
    for (int t = 0; t < K1n; ++t) {
        const float wt = ws[t];               // LDS broadcast
        const f32x2 w2 = {wt, wt};
#pragma unroll
        for (int m = 0; m < 8; ++m)
            acc[m] = __builtin_elementwise_fma(w2, r2[t + m], acc[m]);
    }

    // ---- e interp: the 8 l's lie inside one coarse interval j
    const int j = (l0 + lg) >> 4;
    const float f0 = (float)((l0 + lg) & 15); // 0 or 8
    const float* eb = e + (b * NG + j) * Cdim + c0 + 2 * cp;
    f32x2 z0 = {eb[0], eb[1]};
    f32x2 z1 = {eb[Cdim], eb[Cdim + 1]};
    f32x2 dz = (z1 - z0) * 0.0625f;

    float* ob = out + (b * Ldim + l0 + lg) * Cdim + c0 + 2 * cp;
#pragma unroll
    for (int m = 0; m < 8; ++m) {
        f32x2 itp = __builtin_elementwise_fma(dz, (f32x2)(f0 + (float)m), z0);
        f32x2 r = acc[m] - itp;
        ob[m * Cdim] = r.x;
        ob[m * Cdim + 1] = r.y;
    }
}

// ---- reg-form narrow (middle-fallback path), proven round-3 structure
__global__ __launch_bounds__(256, 2) void narrow_reg_kernel(
        const float* __restrict__ x, const float* __restrict__ w1,
        const float* __restrict__ e, float* __restrict__ out) {
    __shared__ float ws[K1n];
    if (threadIdx.x < K1n) ws[threadIdx.x] = w1[threadIdx.x];
    __syncthreads();

    const int lb = xcd_swizzle(blockIdx.x, gridDim.x);
    const int lin = lb * 256 + threadIdx.x;
    const int c = lin % Cdim;
    const int rest = lin / Cdim;
    const int seg = rest % NSEG;
    const int b = rest / NSEG;
    if (b >= Bdim) return;

    const int l0 = seg * 32;
    const float* xb = x + b * (Ldim * Cdim) + c;

    const int j0 = seg * 2;
    const float* eb = e + (b * NG + j0) * Cdim + c;
    const float z0 = eb[0];
    const float z1 = eb[Cdim];
    const float z2 = eb[2 * Cdim];

    float row[66];
    if (seg >= 1 && seg <= 126) {
        const float* xp = xb + (l0 - R1) * Cdim;
#pragma unroll
        for (int i = 0; i < 66; ++i) row[i] = xp[i * Cdim];
    } else {
#pragma unroll
        for (int i = 0; i < 66; ++i)
            row[i] = xb[mirror_idx(l0 - R1 + i) * Cdim];
    }

    float acc[32];
#pragma unroll
    for (int m = 0; m < 32; ++m) acc[m] = 0.f;
#pragma unroll
    for (int t = 0; t < K1n; ++t) {
        const float wt = ws[t];
#pragma unroll
        for (int m = 0; m < 32; ++m)
            acc[m] = fmaf(wt, row[t + m], acc[m]);
    }

    const float d0 = (z1 - z0) * (1.0f / 16.0f);
    const float d1 = (z2 - z1) * (1.0f / 16.0f);
    float* ob = out + (b * Ldim + l0) * Cdim + c;
#pragma unroll
    for (int m = 0; m < 16; ++m)
        ob[m * Cdim] = acc[m] - fmaf(d0, (float)m, z0);
#pragma unroll
    for (int m = 16; m < 32; ++m)
        ob[m * Cdim] = acc[m] - fmaf(d1, (float)(m - 16), z1);
}

// ---- Middle fallback: direct 769-tap wide conv on the stride-16 grid
#define JPT 16
#define NJG 17
__global__ __launch_bounds__(256, 2) void wide_mid_kernel(
        const float* __restrict__ x, const float* __restrict__ w2p,
        float* __restrict__ z) {
    __shared__ float w2s[784];
    for (int i = threadIdx.x; i < 784; i += 256) w2s[i] = w2p[i];
    __syncthreads();

    const int gid = blockIdx.x * 256 + threadIdx.x;
    const int c = gid % Cdim;
    const int rest = gid / Cdim;
    const int jg = rest % NJG;
    const int b = rest / NJG;
    if (b >= Bdim) return;

    const int j0 = jg * JPT;
    const float* xb = x + b * (Ldim * Cdim) + c;

    float acc[JPT];
#pragma unroll
    for (int jj = 0; jj < JPT; ++jj) acc[jj] = 0.f;

    const bool interior = (j0 >= 24) && (16 * (j0 + 39) + 15 <= Ldim - 1);

#pragma unroll 1
    for (int p = 0; p < 16; ++p) {
        float row[64];
        if (interior) {
            const float* xp = xb + (16 * (j0 - 24) + p) * Cdim;
#pragma unroll
            for (int i = 0; i < 64; ++i) row[i] = xp[i * (16 * Cdim)];
        } else {
#pragma unroll
            for (int i = 0; i < 64; ++i)
                row[i] = xb[mirror_idx(16 * (j0 - 24 + i) + p) * Cdim];
        }
#pragma unroll
        for (int q = 0; q < 49; ++q) {
            const float wq = w2s[q * 16 + p];
#pragma unroll
            for (int jj = 0; jj < JPT; ++jj)
                acc[jj] = fmaf(wq, row[q + jj], acc[jj]);
        }
    }

    float* zb = z + (b * NG + j0) * Cdim + c;
#pragma unroll
    for (int jj = 0; jj < JPT; ++jj)
        if (j0 + jj < NG) zb[jj * Cdim] = acc[jj];
}

// ---- Last-resort fallback: fully direct
__global__ __launch_bounds__(256) void naive_kernel(
        const float* __restrict__ x, const float* __restrict__ w,
        float* __restrict__ out) {
    const int gid = blockIdx.x * 256 + threadIdx.x;
    if (gid >= Bdim * Ldim * Cdim) return;
    const int c = gid % Cdim;
    const int rest = gid / Cdim;
    const int l = rest % Ldim;
    const int b = rest / Ldim;
    const float* xb = x + b * (Ldim * Cdim) + c;
    float a2 = 0.f, a1 = 0.f;
    for (int t = 0; t < K2n; ++t)
        a2 = fmaf(w[K2_OFF + t], xb[mirror_idx(l + t - R2) * Cdim], a2);
#pragma unroll
    for (int t = 0; t < K1n; ++t)
        a1 = fmaf(w[W1_OFF + t], xb[mirror_idx(l + t - R1) * Cdim], a1);
    out[gid] = a1 - a2;
}

extern "C" void kernel_launch(void* const* d_in, const int* in_sizes, int n_in,
                              void* d_out, int out_size, void* d_ws, size_t ws_size,
                              hipStream_t stream) {
    (void)in_sizes; (void)n_in; (void)out_size;
    const float* x = (const float*)d_in[0];
    float* out = (float*)d_out;
    float* w = (float*)d_ws;

    hipLaunchKernelGGL(init_weights_kernel, dim3(1), dim3(1024), 0, stream, w);

    const size_t need_pyr = (size_t)WS_TOT * sizeof(float);
    const size_t need_mid = (size_t)(E2_OFF + Bdim * NG * Cdim) * sizeof(float);

    if (ws_size >= need_pyr) {
        const int a_total = Bdim * NGRP_A * Cdim;      // 205,440
        hipLaunchKernelGGL(decimA_kernel, dim3((a_total + 255) / 256), dim3(256),
                           0, stream, x, w + GA_OFF, w + D_OFF);
        const int b_total = Bdim * NTJ * Cdim;         // 338,976
        hipLaunchKernelGGL(coarseB_kernel, dim3((b_total + 255) / 256), dim3(256),
                           0, stream, w + D_OFF, w + GB_OFF, w + E_OFF);
        const int nblk = Bdim * NCT * NLT;             // 12,288 blocks
        hipLaunchKernelGGL(narrow_lds_kernel, dim3(nblk), dim3(256),
                           0, stream, x, w + W1_OFF, w + E_OFF, out);
    } else if (ws_size >= need_mid) {
        const int wide_total = Bdim * NJG * Cdim;
        hipLaunchKernelGGL(wide_mid_kernel, dim3((wide_total + 255) / 256), dim3(256),
                           0, stream, x, w + K2P_OFF, w + E2_OFF);
        const int nar_total = Bdim * NSEG * Cdim;
        hipLaunchKernelGGL(narrow_reg_kernel, dim3((nar_total + 255) / 256), dim3(256),
                           0, stream, x, w + W1_OFF, w + E2_OFF, out);
    } else {
        const int total = Bdim * Ldim * Cdim;
        hipLaunchKernelGGL(naive_kernel, dim3((total + 255) / 256), dim3(256),
                           0, stream, x, w, out);
    }
}